// Round 9
// baseline (6410.300 us; speedup 1.0000x reference)
//
#include <hip/hip_runtime.h>

typedef unsigned int u32;
typedef unsigned short u16;

#define BG 64
#define NNODE 320
#define NEDGE 1280
#define TT 256
#define FN 64
#define FG 16
#define HM 128
#define HU 128
#define HG 64
#define HA 4
#define ZM 512
#define ZU 512
#define ZG 256
#define ZA 16
#define DM 144
#define DU 208
#define DG 144
#define DA 192

// ---- conversion-area layout (floats, relative to ws+64) ----
#define CV 64
#define O_NODES 0
#define O_GA    20480
#define O_WM    21504
#define O_WHM   95232
#define O_BM    160768
#define O_WU    161280
#define O_WHU   267776
#define O_BU    333312
#define O_WG    333824
#define O_WHG   370688
#define O_BG2   387072
#define O_WA    387328
#define O_WHA   390400
#define O_BA    390464
#define CONV_TOTAL 390480
#define O_XZM   390528
#define O_MSG   (O_XZM + 320 * ZM)
#define O_XZU   (O_XZM + NEDGE * ZM)
#define O_XZG   (O_XZU + NNODE * ZU)
#define O_XZA   (O_XZG + BG * ZG)
#define O_AGGR  (O_XZA + BG * ZA)
#define O_AGGB  (O_AGGR + NNODE * HM)
#define O_UPD   (O_AGGB + BG * HU)
#define WS_FLOATS (CV + O_UPD + NNODE * HU)

__device__ __forceinline__ float bf2f(u16 v) {
  return __uint_as_float(((u32)v) << 16);
}
__device__ __forceinline__ float sigf(float x) { return 1.0f / (1.0f + __expf(-x)); }
__device__ __forceinline__ float tanh_(float x) {
  float e = __expf(-2.0f * fabsf(x));
  float t = (1.0f - e) / (1.0f + e);
  return copysignf(t, x);
}
__device__ __forceinline__ float cvt(const void* p, int i, int flag) {
  return flag ? bf2f(((const u16*)p)[i]) : ((const float*)p)[i];
}

// lgkmcnt-only barrier: orders LDS without __syncthreads()'s vmcnt(0) drain.
#define BAR() asm volatile("s_waitcnt lgkmcnt(0)\n\ts_barrier" ::: "memory")

// 8-lane butterfly sum, all on the VALU pipe (DPP), zero DS-pipe ops:
// quad xor1 (0xB1), quad xor2 (0x4E), row_half_mirror 0x141 (= xor-7 within
// each octet -> combines the two quad-sums; every lane ends with octet sum).
__device__ __forceinline__ float red8(float s) {
  float t;
  t = __uint_as_float(__builtin_amdgcn_update_dpp(
      0, (int)__float_as_uint(s), 0xB1, 0xF, 0xF, true));
  s += t;
  t = __uint_as_float(__builtin_amdgcn_update_dpp(
      0, (int)__float_as_uint(s), 0x4E, 0xF, 0xF, true));
  s += t;
  t = __uint_as_float(__builtin_amdgcn_update_dpp(
      0, (int)__float_as_uint(s), 0x141, 0xF, 0xF, true));
  s += t;
  return s;
}

__device__ __forceinline__ float dot16(
    float4 a0, float4 a1, float4 a2, float4 a3,
    float4 h0, float4 h1, float4 h2, float4 h3) {
  float s0 = a0.x * h0.x; s0 = fmaf(a0.y, h0.y, s0);
  s0 = fmaf(a0.z, h0.z, s0); s0 = fmaf(a0.w, h0.w, s0);
  float s1 = a1.x * h1.x; s1 = fmaf(a1.y, h1.y, s1);
  s1 = fmaf(a1.z, h1.z, s1); s1 = fmaf(a1.w, h1.w, s1);
  float s2 = a2.x * h2.x; s2 = fmaf(a2.y, h2.y, s2);
  s2 = fmaf(a2.z, h2.z, s2); s2 = fmaf(a2.w, h2.w, s2);
  float s3 = a3.x * h3.x; s3 = fmaf(a3.y, h3.y, s3);
  s3 = fmaf(a3.z, h3.z, s3); s3 = fmaf(a3.w, h3.w, s3);
  return (s0 + s1) + (s2 + s3);
}

// ---------------------------------------------------------------------------
// K-1: runtime dtype detector.
// ---------------------------------------------------------------------------
__global__ void k_detect(const u32* __restrict__ raw, int* __restrict__ flagp) {
  const int t = threadIdx.x;
  int zlo = 0, hits = 0;
  for (int k = t; k < 256; k += 64) {
    u32 w = raw[k];
    if ((w & 0xFFFFu) == 0u) zlo++;
    u32 m = (w >> 8) & 0x7Fu;
    if (m >= 40u && m <= 70u) hits++;
  }
#pragma unroll
  for (int off = 32; off; off >>= 1) {
    zlo += __shfl_down(zlo, off, 64);
    hits += __shfl_down(hits, off, 64);
  }
  if (t == 0) *flagp = (zlo < 128 && hits >= 128) ? 1 : 0;
}

// ---------------------------------------------------------------------------
// K0: convert weights/biases (+ t=255 slices) to fp32; Wm/Wu/Wg/Wa transposed.
// ---------------------------------------------------------------------------
__global__ __launch_bounds__(256) void k_convert(
    const void* nodes, const void* gattr,
    const void* Wm, const void* Whm, const void* bm1, const void* bm2,
    const void* Wu, const void* Whu, const void* bu1, const void* bu2,
    const void* Wg, const void* Whg, const void* bg1, const void* bg2,
    const void* Wa, const void* Wha, const void* ba1, const void* ba2,
    const int* __restrict__ flagp, float* __restrict__ dst) {
  const int flag = *flagp;
  const int i = blockIdx.x * 256 + threadIdx.x;
  if (i >= CONV_TOTAL) return;
  float v;
  if (i < O_GA) {
    int n = i >> 6, f = i & 63;
    v = cvt(nodes, (n * TT + (TT - 1)) * FN + f, flag);
  } else if (i < O_WM) {
    int l = i - O_GA; int b = l >> 4, g = l & 15;
    v = cvt(gattr, (b * TT + (TT - 1)) * FG + g, flag);
  } else if (i < O_WHM) {
    int l = i - O_WM; int d = l >> 9, j = l & 511;   // WmT[d][j]
    v = cvt(Wm, j * DM + d, flag);
  } else if (i < O_BM) {
    v = cvt(Whm, i - O_WHM, flag);
  } else if (i < O_WU) {
    int l = i - O_BM; v = cvt(bm1, l, flag) + cvt(bm2, l, flag);
  } else if (i < O_WHU) {
    int l = i - O_WU; int d = l >> 9, j = l & 511;   // WuT[d][j]
    v = cvt(Wu, j * DU + d, flag);
  } else if (i < O_BU) {
    v = cvt(Whu, i - O_WHU, flag);
  } else if (i < O_WG) {
    int l = i - O_BU; v = cvt(bu1, l, flag) + cvt(bu2, l, flag);
  } else if (i < O_WHG) {
    int l = i - O_WG; int d = l >> 8, j = l & 255;   // WgT[d][j]
    v = cvt(Wg, j * DG + d, flag);
  } else if (i < O_BG2) {
    v = cvt(Whg, i - O_WHG, flag);
  } else if (i < O_WA) {
    int l = i - O_BG2; v = cvt(bg1, l, flag) + cvt(bg2, l, flag);
  } else if (i < O_WHA) {
    int l = i - O_WA; int d = l >> 4, j = l & 15;    // WaT[d][j]
    v = cvt(Wa, j * DA + d, flag);
  } else if (i < O_BA) {
    v = cvt(Wha, i - O_WHA, flag);
  } else {
    int l = i - O_BA; v = cvt(ba1, l, flag) + cvt(ba2, l, flag);
  }
  dst[i] = v;
}

// ---------------------------------------------------------------------------
// K1: input projections at t=T-1 with transposed weights (coalesced).
// ---------------------------------------------------------------------------
__global__ __launch_bounds__(256) void k_pre(
    const float* __restrict__ cva, const int* __restrict__ num_nodes,
    float* __restrict__ XZmU, float* __restrict__ XZu, float* __restrict__ XZg) {
  const int blk = blockIdx.x, tid = threadIdx.x;
  __shared__ float xv[FN];
  __shared__ float gav[FG];
  __shared__ int sgr;
  const float* nodes255 = cva + O_NODES;
  const float* ga255 = cva + O_GA;

  if (blk < 2 * NNODE) {
    const int n = (blk < NNODE) ? blk : (blk - NNODE);
    if (tid == 0) {
      int g = 0, acc = 0;
      while (g < BG) { int c = num_nodes[g]; if (n < acc + c) break; acc += c; ++g; }
      if (g >= BG) g = BG - 1;
      sgr = g;
    }
    if (tid < FN) xv[tid] = nodes255[n * FN + tid];
    __syncthreads();
    if (tid < FG) gav[tid] = ga255[sgr * FG + tid];
    __syncthreads();
    const int j0 = 2 * tid;
    if (blk < NNODE) {
      float2 acc = *(const float2*)&cva[O_BM + j0];
#pragma unroll 8
      for (int d = 0; d < FN; ++d) {
        float2 wa = *(const float2*)&cva[O_WM + d * 512 + j0];
        float2 wb = *(const float2*)&cva[O_WM + (FN + d) * 512 + j0];
        float x = xv[d];
        acc.x += (wa.x + wb.x) * x;
        acc.y += (wa.y + wb.y) * x;
      }
#pragma unroll
      for (int d = 0; d < FG; ++d) {
        float2 wc = *(const float2*)&cva[O_WM + (2 * FN + d) * 512 + j0];
        float x = gav[d];
        acc.x += wc.x * x;
        acc.y += wc.y * x;
      }
      *(float2*)&XZmU[(size_t)n * ZM + j0] = acc;
    } else {
      float2 acc = *(const float2*)&cva[O_BU + j0];
#pragma unroll 8
      for (int d = 0; d < FN; ++d) {
        float2 wa = *(const float2*)&cva[O_WU + d * 512 + j0];
        float x = xv[d];
        acc.x += wa.x * x;
        acc.y += wa.y * x;
      }
#pragma unroll
      for (int d = 0; d < FG; ++d) {
        float2 wc = *(const float2*)&cva[O_WU + (FN + HM + d) * 512 + j0];
        float x = gav[d];
        acc.x += wc.x * x;
        acc.y += wc.y * x;
      }
      *(float2*)&XZu[(size_t)n * ZU + j0] = acc;
    }
  } else {
    const int b = blk - 2 * NNODE;
    if (tid < FG) gav[tid] = ga255[b * FG + tid];
    __syncthreads();
    float acc = cva[O_BG2 + tid];
#pragma unroll
    for (int d = 0; d < FG; ++d)
      acc += cva[O_WG + (HU + d) * 256 + tid] * gav[d];
    XZg[(size_t)b * ZG + tid] = acc;
  }
}

// ---------------------------------------------------------------------------
// K2/K4: LSTM chain. 1024 threads (16 waves = exactly 4 waves/EU).
// 8 lanes per element: lane8 = col-chunk of 16. Each thread holds 4 gate-rows
// x 16 cols = 16 NAMED float4s (no array -> no alloca -> guaranteed SSA).
// Pressure ~110 VGPRs < 128 budget at 4 waves/EU. Rounds 5-8 proved
// per-thread ARRAYS always spill (VGPR 84-96, step time == L2-BW model of
// 256KB/step scratch reload); named scalars are the fix.
// 8-lane reduce = 3 DPP ops (VALU pipe). h in padded LDS (chunk stride 20:
// b128 reads hit all 32 banks at 2 lanes/bank = conflict-free).
// ---------------------------------------------------------------------------
template <int STEPS, bool IDX>
__global__ __attribute__((amdgpu_waves_per_eu(4, 4))) __launch_bounds__(1024)
void k_chain2(const float* __restrict__ Whh, const float* __restrict__ XZ,
              const int* __restrict__ eidx, float* __restrict__ hout) {
  const int lane = threadIdx.x & 63;
  const int wv = threadIdx.x >> 6;   // 0..15
  const int c = lane & 7;            // col chunk: cols [c*16, c*16+16)
  const int eg = lane >> 3;          // 0..7
  const int elem = wv * 8 + eg;      // 0..127
  __shared__ float hbuf[2][160];     // 8 chunks x 20 floats (4-pad)

  const float* b0 = Whh + ((size_t)(0 * 128 + elem) * 128) + c * 16;
  const float* b1 = Whh + ((size_t)(1 * 128 + elem) * 128) + c * 16;
  const float* b2 = Whh + ((size_t)(2 * 128 + elem) * 128) + c * 16;
  const float* b3 = Whh + ((size_t)(3 * 128 + elem) * 128) + c * 16;
  const float4 wa0 = ((const float4*)b0)[0], wa1 = ((const float4*)b0)[1],
               wa2 = ((const float4*)b0)[2], wa3 = ((const float4*)b0)[3];
  const float4 wb0 = ((const float4*)b1)[0], wb1 = ((const float4*)b1)[1],
               wb2 = ((const float4*)b1)[2], wb3 = ((const float4*)b1)[3];
  const float4 wc0 = ((const float4*)b2)[0], wc1 = ((const float4*)b2)[1],
               wc2 = ((const float4*)b2)[2], wc3 = ((const float4*)b2)[3];
  const float4 wd0 = ((const float4*)b3)[0], wd1 = ((const float4*)b3)[1],
               wd2 = ((const float4*)b3)[2], wd3 = ((const float4*)b3)[3];

  if (threadIdx.x < 320) ((float*)hbuf)[threadIdx.x] = 0.0f;
  float cc = 0.0f;
  float xz0, xz1, xz2, xz3;
  {
    const int s0 = IDX ? eidx[0] : 0;
    const float* xp = XZ + (size_t)s0 * 512;
    xz0 = xp[0 * 128 + elem]; xz1 = xp[1 * 128 + elem];
    xz2 = xp[2 * 128 + elem]; xz3 = xp[3 * 128 + elem];
  }
  BAR();
  int cur = 0;
  for (int e = 0; e < STEPS; ++e) {
    const float4* hb = (const float4*)&hbuf[cur][c * 20];
    const float4 h0 = hb[0], h1 = hb[1], h2 = hb[2], h3 = hb[3];
    float z0 = xz0 + red8(dot16(wa0, wa1, wa2, wa3, h0, h1, h2, h3));
    float z1 = xz1 + red8(dot16(wb0, wb1, wb2, wb3, h0, h1, h2, h3));
    float z2 = xz2 + red8(dot16(wc0, wc1, wc2, wc3, h0, h1, h2, h3));
    float z3 = xz3 + red8(dot16(wd0, wd1, wd2, wd3, h0, h1, h2, h3));
    if (e + 1 < STEPS) {
      const int sn = IDX ? eidx[e + 1] : (e + 1);
      const float* xp = XZ + (size_t)sn * 512;
      xz0 = xp[0 * 128 + elem]; xz1 = xp[1 * 128 + elem];
      xz2 = xp[2 * 128 + elem]; xz3 = xp[3 * 128 + elem];
    }
    // gates: z0=i, z1=f, z2=g, z3=o (replicated across the octet)
    cc = sigf(z1) * cc + sigf(z0) * tanh_(z2);
    float h = sigf(z3) * tanh_(cc);
    if (c == 0) {
      hbuf[cur ^ 1][(elem >> 4) * 20 + (elem & 15)] = h;
      hout[(size_t)e * 128 + elem] = fmaxf(h, 0.0f);
    }
    BAR();
    cur ^= 1;
  }
}

// ---------------------------------------------------------------------------
// K3: fused segment_min + projection: aggr[n]=min msg over eidx==n (LDS),
// then XZu[n] += WuT[64:192] @ aggr[n]. 320 blocks x 256 threads.
// ---------------------------------------------------------------------------
__global__ __launch_bounds__(256) void k_aggfuse(
    const float* __restrict__ cva, const float* __restrict__ msg,
    const int* __restrict__ eidx, float* __restrict__ XZu) {
  const int n = blockIdx.x, tid = threadIdx.x;
  __shared__ float av[HM];
  if (tid < HM) {
    float m = __uint_as_float(0x7f800000u);
    for (int e = 0; e < NEDGE; ++e)
      if (eidx[e] == n) m = fminf(m, msg[(size_t)e * HM + tid]);
    av[tid] = m;
  }
  __syncthreads();
  const int j0 = 2 * tid;
  float2 acc = *(float2*)&XZu[(size_t)n * ZU + j0];
#pragma unroll 8
  for (int k = 0; k < HM; ++k) {
    float2 w = *(const float2*)&cva[O_WU + (FN + k) * 512 + j0];
    float a = av[k];
    acc.x += w.x * a;
    acc.y += w.y * a;
  }
  *(float2*)&XZu[(size_t)n * ZU + j0] = acc;
}

// ---------------------------------------------------------------------------
// K5: blocks [0,64): XZg[b] += WgT[0:128] @ aggB[b] (aggB computed locally)
//     blocks [64,128): XZa[b] = WaT[0:128] @ chosen[b] + biases
// ---------------------------------------------------------------------------
__global__ __launch_bounds__(256) void k_gproj(
    const float* __restrict__ cva, const float* __restrict__ upd,
    const int* __restrict__ bidx, const int* __restrict__ who,
    float* __restrict__ XZg, float* __restrict__ XZa) {
  const int blk = blockIdx.x, tid = threadIdx.x;
  const int b = (blk < BG) ? blk : (blk - BG);
  __shared__ float buf[HU];
  __shared__ float cho[HU];
  __shared__ int satbw;
  if (tid < HU) {
    float m = __uint_as_float(0x7f800000u);
    for (int nn = 0; nn < NNODE; ++nn)
      if (bidx[nn] == b) m = fminf(m, upd[(size_t)nn * HU + tid]);
    buf[tid] = m;
  }
  __syncthreads();
  if (blk < BG) {
    float acc = 0.0f;
#pragma unroll 8
    for (int k = 0; k < HU; ++k) acc += cva[O_WG + k * 256 + tid] * buf[k];
    XZg[(size_t)b * ZG + tid] += acc;
  } else {
    const int whoB = who[b];
    if (tid == 0) {
      int off = 0;
      for (int i = 0; i < NNODE; ++i) off += (bidx[i] < b) ? 1 : 0;
      const int adj = (whoB == 3) ? 2 : whoB;
      satbw = (b == 0) ? who[0] : (adj + off);
    }
    __syncthreads();
    if (tid < HU) cho[tid] = (whoB == 3) ? buf[tid] : upd[(size_t)satbw * HU + tid];
    __syncthreads();
    if (tid < ZA) {
      float acc = cva[O_BA + tid];
#pragma unroll 8
      for (int k = 0; k < HU; ++k) acc += cva[O_WA + k * 16 + tid] * cho[k];
      XZa[(size_t)b * ZA + tid] = acc;
    }
  }
}

// ---------------------------------------------------------------------------
// K6: group LSTM chain + action chain + softmax + fp32 out. 1 block x 256.
// ---------------------------------------------------------------------------
__global__ __launch_bounds__(256, 2) void k_final(
    const float* __restrict__ cva, const float* __restrict__ XZg,
    const float* __restrict__ XZa, float* __restrict__ out) {
  const int j = threadIdx.x;
  __shared__ __align__(16) float hg[HG];
  __shared__ float zsg[ZG];
  __shared__ float grp[BG * HG];
  __shared__ float za[ZA];
  __shared__ float haL[HA];
  __shared__ float res[BG * HA];

  float wg[HG];
  {
    const float* wr = cva + O_WHG + j * HG;
#pragma unroll
    for (int k = 0; k < HG; ++k) wg[k] = wr[k];
  }
  if (j < HG) hg[j] = 0.0f;
  float cg = 0.0f;
  __syncthreads();
  for (int b = 0; b < BG; ++b) {
    float acc = XZg[(size_t)b * ZG + j];
#pragma unroll
    for (int k = 0; k < HG; ++k) acc += wg[k] * hg[k];
    zsg[j] = acc;
    __syncthreads();
    if (j < HG) {
      float zi = zsg[j], zf = zsg[HG + j], zg = zsg[2 * HG + j], zo = zsg[3 * HG + j];
      cg = sigf(zf) * cg + sigf(zi) * tanh_(zg);
      float h = sigf(zo) * tanh_(cg);
      hg[j] = h;
      grp[b * HG + j] = fmaxf(h, 0.0f);
    }
    __syncthreads();
  }

  float wa2[HG];
  float wha[HA];
  if (j < ZA) {
#pragma unroll
    for (int k = 0; k < HG; ++k) wa2[k] = cva[O_WA + (HU + k) * 16 + j];
#pragma unroll
    for (int k = 0; k < HA; ++k) wha[k] = cva[O_WHA + j * HA + k];
  }
  if (j < HA) haL[j] = 0.0f;
  float ca = 0.0f;
  __syncthreads();
  for (int b = 0; b < BG; ++b) {
    if (j < ZA) {
      float acc = XZa[(size_t)b * ZA + j];
#pragma unroll
      for (int k = 0; k < HG; ++k) acc += wa2[k] * grp[b * HG + k];
#pragma unroll
      for (int k = 0; k < HA; ++k) acc += wha[k] * haL[k];
      za[j] = acc;
    }
    __syncthreads();
    if (j < HA) {
      float zi = za[j], zf = za[HA + j], zg = za[2 * HA + j], zo = za[3 * HA + j];
      ca = sigf(zf) * ca + sigf(zi) * tanh_(zg);
      float h = sigf(zo) * tanh_(ca);
      haL[j] = h;
      res[b * HA + j] = h;
    }
    __syncthreads();
  }
  if (j < BG) {
    float x0 = res[j * 4 + 0], x1 = res[j * 4 + 1];
    float x2 = res[j * 4 + 2], x3 = res[j * 4 + 3];
    float m = fmaxf(fmaxf(x0, x1), fmaxf(x2, x3));
    float e0 = __expf(x0 - m), e1 = __expf(x1 - m);
    float e2 = __expf(x2 - m), e3 = __expf(x3 - m);
    float s = e0 + e1 + e2 + e3;
    out[j * 4 + 0] = e0 / s;
    out[j * 4 + 1] = e1 / s;
    out[j * 4 + 2] = e2 / s;
    out[j * 4 + 3] = e3 / s;
  }
}

__global__ void k_zero(float* out) { out[threadIdx.x] = 0.0f; }

extern "C" void kernel_launch(void* const* d_in, const int* in_sizes, int n_in,
                              void* d_out, int out_size, void* d_ws, size_t ws_size,
                              hipStream_t stream) {
  const void* nodes = d_in[0];
  const int* eidx  = (const int*)d_in[2];
  const int* nn    = (const int*)d_in[3];
  const int* bidx  = (const int*)d_in[5];
  const int* who   = (const int*)d_in[6];

  if (ws_size < (size_t)WS_FLOATS * 4) {
    k_zero<<<1, 256, 0, stream>>>((float*)d_out);
    return;
  }

  float* ws = (float*)d_ws;
  int* flagp = (int*)d_ws;
  float* cva = ws + CV;
  float* XZmU = cva + O_XZM;   // 320 x 512 (unique per src node)
  float* msg  = cva + O_MSG;   // 1280 x 128
  float* XZu = cva + O_XZU;
  float* XZg = cva + O_XZG;
  float* XZa = cva + O_XZA;
  float* upd = cva + O_UPD;

  k_detect<<<1, 64, 0, stream>>>((const u32*)nodes, flagp);
  k_convert<<<(CONV_TOTAL + 255) / 256, 256, 0, stream>>>(
      nodes, d_in[1],
      d_in[7], d_in[8], d_in[9], d_in[10],
      d_in[11], d_in[12], d_in[13], d_in[14],
      d_in[15], d_in[16], d_in[17], d_in[18],
      d_in[19], d_in[20], d_in[21], d_in[22],
      flagp, cva);
  k_pre<<<2 * NNODE + BG, 256, 0, stream>>>(cva, nn, XZmU, XZu, XZg);
  k_chain2<NEDGE, true><<<1, 1024, 0, stream>>>(cva + O_WHM, XZmU, eidx, msg);
  k_aggfuse<<<NNODE, 256, 0, stream>>>(cva, msg, eidx, XZu);
  k_chain2<NNODE, false><<<1, 1024, 0, stream>>>(cva + O_WHU, XZu, nullptr, upd);
  k_gproj<<<2 * BG, 256, 0, stream>>>(cva, upd, bidx, who, XZg, XZa);
  k_final<<<1, 256, 0, stream>>>(cva, XZg, XZa, (float*)d_out);
}

// Round 11
// 2115.873 us; speedup vs baseline: 3.0296x; 3.0296x over previous
//
#include <hip/hip_runtime.h>

typedef unsigned int u32;
typedef unsigned short u16;

#define BG 64
#define NNODE 320
#define NEDGE 1280
#define TT 256
#define FN 64
#define FG 16
#define HM 128
#define HU 128
#define HG 64
#define HA 4
#define ZM 512
#define ZU 512
#define ZG 256
#define ZA 16
#define DM 144
#define DU 208
#define DG 144
#define DA 192

// ---- conversion-area layout (floats, relative to ws+64) ----
#define CV 64
#define O_NODES 0
#define O_GA    20480
#define O_WM    21504
#define O_WHM   95232
#define O_BM    160768
#define O_WU    161280
#define O_WHU   267776
#define O_BU    333312
#define O_WG    333824
#define O_WHG   370688
#define O_BG2   387072
#define O_WA    387328
#define O_WHA   390400
#define O_BA    390464
#define CONV_TOTAL 390480
#define O_XZM   390528
#define O_MSG   (O_XZM + 320 * ZM)
#define O_XZU   (O_XZM + NEDGE * ZM)
#define O_XZG   (O_XZU + NNODE * ZU)
#define O_XZA   (O_XZG + BG * ZG)
#define O_AGGR  (O_XZA + BG * ZA)
#define O_AGGB  (O_AGGR + NNODE * HM)
#define O_UPD   (O_AGGB + BG * HU)
#define WS_FLOATS (CV + O_UPD + NNODE * HU)

__device__ __forceinline__ float bf2f(u16 v) {
  return __uint_as_float(((u32)v) << 16);
}
__device__ __forceinline__ float sigf(float x) { return 1.0f / (1.0f + __expf(-x)); }
__device__ __forceinline__ float tanh_(float x) {
  float e = __expf(-2.0f * fabsf(x));
  float t = (1.0f - e) / (1.0f + e);
  return copysignf(t, x);
}
__device__ __forceinline__ float cvt(const void* p, int i, int flag) {
  return flag ? bf2f(((const u16*)p)[i]) : ((const float*)p)[i];
}

// lgkmcnt-only barrier: orders LDS without __syncthreads()'s vmcnt(0) drain.
#define BAR() asm volatile("s_waitcnt lgkmcnt(0)\n\ts_barrier" ::: "memory")

// 8-lane butterfly sum on the VALU pipe (DPP): quad xor1 (0xB1), quad xor2
// (0x4E), row_half_mirror 0x141 (mirror within octet = combines quad sums).
__device__ __forceinline__ float red8(float s) {
  float t;
  t = __uint_as_float(__builtin_amdgcn_update_dpp(
      0, (int)__float_as_uint(s), 0xB1, 0xF, 0xF, true));
  s += t;
  t = __uint_as_float(__builtin_amdgcn_update_dpp(
      0, (int)__float_as_uint(s), 0x4E, 0xF, 0xF, true));
  s += t;
  t = __uint_as_float(__builtin_amdgcn_update_dpp(
      0, (int)__float_as_uint(s), 0x141, 0xF, 0xF, true));
  s += t;
  return s;
}

// 16 NAMED scalar weights per gate row (no arrays -> no alloca).
#define DECL16(p) \
  float p##0, p##1, p##2, p##3, p##4, p##5, p##6, p##7, \
        p##8, p##9, p##10, p##11, p##12, p##13, p##14, p##15
#define LOAD16(p, base) \
  p##0 = (base)[0];  p##1 = (base)[1];  p##2 = (base)[2];  p##3 = (base)[3]; \
  p##4 = (base)[4];  p##5 = (base)[5];  p##6 = (base)[6];  p##7 = (base)[7]; \
  p##8 = (base)[8];  p##9 = (base)[9];  p##10 = (base)[10]; p##11 = (base)[11]; \
  p##12 = (base)[12]; p##13 = (base)[13]; p##14 = (base)[14]; p##15 = (base)[15]
// Opaque pin on SCALAR floats (single-register tied operands — supported;
// float4 "+v" was rejected as "tied indirect"). Values now originate from
// asm, so the RA cannot rematerialize them from memory inside the loop.
#define PIN16(p) \
  asm("" : "+v"(p##0), "+v"(p##1), "+v"(p##2), "+v"(p##3), \
           "+v"(p##4), "+v"(p##5), "+v"(p##6), "+v"(p##7), \
           "+v"(p##8), "+v"(p##9), "+v"(p##10), "+v"(p##11), \
           "+v"(p##12), "+v"(p##13), "+v"(p##14), "+v"(p##15))
#define DOT16S(p, h0, h1, h2, h3) ({ \
  float _s0 = p##0 * (h0).x;  _s0 = fmaf(p##1, (h0).y, _s0); \
  _s0 = fmaf(p##2, (h0).z, _s0); _s0 = fmaf(p##3, (h0).w, _s0); \
  float _s1 = p##4 * (h1).x;  _s1 = fmaf(p##5, (h1).y, _s1); \
  _s1 = fmaf(p##6, (h1).z, _s1); _s1 = fmaf(p##7, (h1).w, _s1); \
  float _s2 = p##8 * (h2).x;  _s2 = fmaf(p##9, (h2).y, _s2); \
  _s2 = fmaf(p##10, (h2).z, _s2); _s2 = fmaf(p##11, (h2).w, _s2); \
  float _s3 = p##12 * (h3).x; _s3 = fmaf(p##13, (h3).y, _s3); \
  _s3 = fmaf(p##14, (h3).z, _s3); _s3 = fmaf(p##15, (h3).w, _s3); \
  (_s0 + _s1) + (_s2 + _s3); })

// ---------------------------------------------------------------------------
// K-1: runtime dtype detector.
// ---------------------------------------------------------------------------
__global__ void k_detect(const u32* __restrict__ raw, int* __restrict__ flagp) {
  const int t = threadIdx.x;
  int zlo = 0, hits = 0;
  for (int k = t; k < 256; k += 64) {
    u32 w = raw[k];
    if ((w & 0xFFFFu) == 0u) zlo++;
    u32 m = (w >> 8) & 0x7Fu;
    if (m >= 40u && m <= 70u) hits++;
  }
#pragma unroll
  for (int off = 32; off; off >>= 1) {
    zlo += __shfl_down(zlo, off, 64);
    hits += __shfl_down(hits, off, 64);
  }
  if (t == 0) *flagp = (zlo < 128 && hits >= 128) ? 1 : 0;
}

// ---------------------------------------------------------------------------
// K0: convert weights/biases (+ t=255 slices) to fp32; Wm/Wu/Wg/Wa transposed.
// ---------------------------------------------------------------------------
__global__ __launch_bounds__(256) void k_convert(
    const void* nodes, const void* gattr,
    const void* Wm, const void* Whm, const void* bm1, const void* bm2,
    const void* Wu, const void* Whu, const void* bu1, const void* bu2,
    const void* Wg, const void* Whg, const void* bg1, const void* bg2,
    const void* Wa, const void* Wha, const void* ba1, const void* ba2,
    const int* __restrict__ flagp, float* __restrict__ dst) {
  const int flag = *flagp;
  const int i = blockIdx.x * 256 + threadIdx.x;
  if (i >= CONV_TOTAL) return;
  float v;
  if (i < O_GA) {
    int n = i >> 6, f = i & 63;
    v = cvt(nodes, (n * TT + (TT - 1)) * FN + f, flag);
  } else if (i < O_WM) {
    int l = i - O_GA; int b = l >> 4, g = l & 15;
    v = cvt(gattr, (b * TT + (TT - 1)) * FG + g, flag);
  } else if (i < O_WHM) {
    int l = i - O_WM; int d = l >> 9, j = l & 511;   // WmT[d][j]
    v = cvt(Wm, j * DM + d, flag);
  } else if (i < O_BM) {
    v = cvt(Whm, i - O_WHM, flag);
  } else if (i < O_WU) {
    int l = i - O_BM; v = cvt(bm1, l, flag) + cvt(bm2, l, flag);
  } else if (i < O_WHU) {
    int l = i - O_WU; int d = l >> 9, j = l & 511;   // WuT[d][j]
    v = cvt(Wu, j * DU + d, flag);
  } else if (i < O_BU) {
    v = cvt(Whu, i - O_WHU, flag);
  } else if (i < O_WG) {
    int l = i - O_BU; v = cvt(bu1, l, flag) + cvt(bu2, l, flag);
  } else if (i < O_WHG) {
    int l = i - O_WG; int d = l >> 8, j = l & 255;   // WgT[d][j]
    v = cvt(Wg, j * DG + d, flag);
  } else if (i < O_BG2) {
    v = cvt(Whg, i - O_WHG, flag);
  } else if (i < O_WA) {
    int l = i - O_BG2; v = cvt(bg1, l, flag) + cvt(bg2, l, flag);
  } else if (i < O_WHA) {
    int l = i - O_WA; int d = l >> 4, j = l & 15;    // WaT[d][j]
    v = cvt(Wa, j * DA + d, flag);
  } else if (i < O_BA) {
    v = cvt(Wha, i - O_WHA, flag);
  } else {
    int l = i - O_BA; v = cvt(ba1, l, flag) + cvt(ba2, l, flag);
  }
  dst[i] = v;
}

// ---------------------------------------------------------------------------
// K1: input projections at t=T-1 with transposed weights (coalesced).
// ---------------------------------------------------------------------------
__global__ __launch_bounds__(256) void k_pre(
    const float* __restrict__ cva, const int* __restrict__ num_nodes,
    float* __restrict__ XZmU, float* __restrict__ XZu, float* __restrict__ XZg) {
  const int blk = blockIdx.x, tid = threadIdx.x;
  __shared__ float xv[FN];
  __shared__ float gav[FG];
  __shared__ int sgr;
  const float* nodes255 = cva + O_NODES;
  const float* ga255 = cva + O_GA;

  if (blk < 2 * NNODE) {
    const int n = (blk < NNODE) ? blk : (blk - NNODE);
    if (tid == 0) {
      int g = 0, acc = 0;
      while (g < BG) { int c = num_nodes[g]; if (n < acc + c) break; acc += c; ++g; }
      if (g >= BG) g = BG - 1;
      sgr = g;
    }
    if (tid < FN) xv[tid] = nodes255[n * FN + tid];
    __syncthreads();
    if (tid < FG) gav[tid] = ga255[sgr * FG + tid];
    __syncthreads();
    const int j0 = 2 * tid;
    if (blk < NNODE) {
      float2 acc = *(const float2*)&cva[O_BM + j0];
#pragma unroll 8
      for (int d = 0; d < FN; ++d) {
        float2 wa = *(const float2*)&cva[O_WM + d * 512 + j0];
        float2 wb = *(const float2*)&cva[O_WM + (FN + d) * 512 + j0];
        float x = xv[d];
        acc.x += (wa.x + wb.x) * x;
        acc.y += (wa.y + wb.y) * x;
      }
#pragma unroll
      for (int d = 0; d < FG; ++d) {
        float2 wc = *(const float2*)&cva[O_WM + (2 * FN + d) * 512 + j0];
        float x = gav[d];
        acc.x += wc.x * x;
        acc.y += wc.y * x;
      }
      *(float2*)&XZmU[(size_t)n * ZM + j0] = acc;
    } else {
      float2 acc = *(const float2*)&cva[O_BU + j0];
#pragma unroll 8
      for (int d = 0; d < FN; ++d) {
        float2 wa = *(const float2*)&cva[O_WU + d * 512 + j0];
        float x = xv[d];
        acc.x += wa.x * x;
        acc.y += wa.y * x;
      }
#pragma unroll
      for (int d = 0; d < FG; ++d) {
        float2 wc = *(const float2*)&cva[O_WU + (FN + HM + d) * 512 + j0];
        float x = gav[d];
        acc.x += wc.x * x;
        acc.y += wc.y * x;
      }
      *(float2*)&XZu[(size_t)n * ZU + j0] = acc;
    }
  } else {
    const int b = blk - 2 * NNODE;
    if (tid < FG) gav[tid] = ga255[b * FG + tid];
    __syncthreads();
    float acc = cva[O_BG2 + tid];
#pragma unroll
    for (int d = 0; d < FG; ++d)
      acc += cva[O_WG + (HU + d) * 256 + tid] * gav[d];
    XZg[(size_t)b * ZG + tid] = acc;
  }
}

// ---------------------------------------------------------------------------
// K2/K4: LSTM chain. 1024 threads (16 waves = 4/EU -> VGPR cap 128).
// 8 lanes per element; thread holds 4 gate-rows x 16 cols = 64 NAMED scalar
// floats. Anti-spill (rounds 5-10 post-mortem):
//  (1) #pragma unroll 1 on the step loop (unrolling multiplied live ranges ->
//      RA demoted weights; VGPR 64-96 + L2 scratch reloads = 1.26-3.85us/step)
//  (2) opaque asm pin of the 64 scalars (4 x 16-operand asm; float4 "+v"
//      doesn't compile - "tied indirect").
// 8-lane reduce = 3 DPP ops (VALU pipe). h in padded LDS (stride 20).
// ---------------------------------------------------------------------------
template <int STEPS, bool IDX>
__global__ __attribute__((amdgpu_waves_per_eu(4, 4))) __launch_bounds__(1024)
void k_chain2(const float* __restrict__ Whh, const float* __restrict__ XZ,
              const int* __restrict__ eidx, float* __restrict__ hout) {
  const int lane = threadIdx.x & 63;
  const int wv = threadIdx.x >> 6;   // 0..15
  const int c = lane & 7;            // col chunk: cols [c*16, c*16+16)
  const int eg = lane >> 3;          // 0..7
  const int elem = wv * 8 + eg;      // 0..127
  __shared__ float hbuf[2][160];     // 8 chunks x 20 floats (4-pad)

  const float* b0 = Whh + ((size_t)(0 * 128 + elem) * 128) + c * 16;
  const float* b1 = Whh + ((size_t)(1 * 128 + elem) * 128) + c * 16;
  const float* b2 = Whh + ((size_t)(2 * 128 + elem) * 128) + c * 16;
  const float* b3 = Whh + ((size_t)(3 * 128 + elem) * 128) + c * 16;
  DECL16(wa); DECL16(wb); DECL16(wc); DECL16(wd);
  LOAD16(wa, b0); LOAD16(wb, b1); LOAD16(wc, b2); LOAD16(wd, b3);
  PIN16(wa); PIN16(wb); PIN16(wc); PIN16(wd);

  if (threadIdx.x < 320) ((float*)hbuf)[threadIdx.x] = 0.0f;
  float cc = 0.0f;
  float xz0, xz1, xz2, xz3;
  {
    const int s0 = IDX ? eidx[0] : 0;
    const float* xp = XZ + (size_t)s0 * 512;
    xz0 = xp[0 * 128 + elem]; xz1 = xp[1 * 128 + elem];
    xz2 = xp[2 * 128 + elem]; xz3 = xp[3 * 128 + elem];
  }
  BAR();
  int cur = 0;
#pragma unroll 1
  for (int e = 0; e < STEPS; ++e) {
    const float4* hb = (const float4*)&hbuf[cur][c * 20];
    const float4 h0 = hb[0], h1 = hb[1], h2 = hb[2], h3 = hb[3];
    float z0 = xz0 + red8(DOT16S(wa, h0, h1, h2, h3));
    float z1 = xz1 + red8(DOT16S(wb, h0, h1, h2, h3));
    float z2 = xz2 + red8(DOT16S(wc, h0, h1, h2, h3));
    float z3 = xz3 + red8(DOT16S(wd, h0, h1, h2, h3));
    if (e + 1 < STEPS) {
      const int sn = IDX ? eidx[e + 1] : (e + 1);
      const float* xp = XZ + (size_t)sn * 512;
      xz0 = xp[0 * 128 + elem]; xz1 = xp[1 * 128 + elem];
      xz2 = xp[2 * 128 + elem]; xz3 = xp[3 * 128 + elem];
    }
    // gates: z0=i, z1=f, z2=g, z3=o (replicated across the octet)
    cc = sigf(z1) * cc + sigf(z0) * tanh_(z2);
    float h = sigf(z3) * tanh_(cc);
    if (c == 0) {
      hbuf[cur ^ 1][(elem >> 4) * 20 + (elem & 15)] = h;
      hout[(size_t)e * 128 + elem] = fmaxf(h, 0.0f);
    }
    BAR();
    cur ^= 1;
  }
}

// ---------------------------------------------------------------------------
// K3: fused segment_min + projection.
// ---------------------------------------------------------------------------
__global__ __launch_bounds__(256) void k_aggfuse(
    const float* __restrict__ cva, const float* __restrict__ msg,
    const int* __restrict__ eidx, float* __restrict__ XZu) {
  const int n = blockIdx.x, tid = threadIdx.x;
  __shared__ float av[HM];
  if (tid < HM) {
    float m = __uint_as_float(0x7f800000u);
    for (int e = 0; e < NEDGE; ++e)
      if (eidx[e] == n) m = fminf(m, msg[(size_t)e * HM + tid]);
    av[tid] = m;
  }
  __syncthreads();
  const int j0 = 2 * tid;
  float2 acc = *(float2*)&XZu[(size_t)n * ZU + j0];
#pragma unroll 8
  for (int k = 0; k < HM; ++k) {
    float2 w = *(const float2*)&cva[O_WU + (FN + k) * 512 + j0];
    float a = av[k];
    acc.x += w.x * a;
    acc.y += w.y * a;
  }
  *(float2*)&XZu[(size_t)n * ZU + j0] = acc;
}

// ---------------------------------------------------------------------------
// K5: blocks [0,64): XZg += WgT @ aggB; [64,128): XZa = WaT @ chosen + bias
// ---------------------------------------------------------------------------
__global__ __launch_bounds__(256) void k_gproj(
    const float* __restrict__ cva, const float* __restrict__ upd,
    const int* __restrict__ bidx, const int* __restrict__ who,
    float* __restrict__ XZg, float* __restrict__ XZa) {
  const int blk = blockIdx.x, tid = threadIdx.x;
  const int b = (blk < BG) ? blk : (blk - BG);
  __shared__ float buf[HU];
  __shared__ float cho[HU];
  __shared__ int satbw;
  if (tid < HU) {
    float m = __uint_as_float(0x7f800000u);
    for (int nn = 0; nn < NNODE; ++nn)
      if (bidx[nn] == b) m = fminf(m, upd[(size_t)nn * HU + tid]);
    buf[tid] = m;
  }
  __syncthreads();
  if (blk < BG) {
    float acc = 0.0f;
#pragma unroll 8
    for (int k = 0; k < HU; ++k) acc += cva[O_WG + k * 256 + tid] * buf[k];
    XZg[(size_t)b * ZG + tid] += acc;
  } else {
    const int whoB = who[b];
    if (tid == 0) {
      int off = 0;
      for (int i = 0; i < NNODE; ++i) off += (bidx[i] < b) ? 1 : 0;
      const int adj = (whoB == 3) ? 2 : whoB;
      satbw = (b == 0) ? who[0] : (adj + off);
    }
    __syncthreads();
    if (tid < HU) cho[tid] = (whoB == 3) ? buf[tid] : upd[(size_t)satbw * HU + tid];
    __syncthreads();
    if (tid < ZA) {
      float acc = cva[O_BA + tid];
#pragma unroll 8
      for (int k = 0; k < HU; ++k) acc += cva[O_WA + k * 16 + tid] * cho[k];
      XZa[(size_t)b * ZA + tid] = acc;
    }
  }
}

// ---------------------------------------------------------------------------
// K6: group LSTM chain + action chain + softmax + fp32 out. 1 block x 256.
// ---------------------------------------------------------------------------
__global__ __launch_bounds__(256, 2) void k_final(
    const float* __restrict__ cva, const float* __restrict__ XZg,
    const float* __restrict__ XZa, float* __restrict__ out) {
  const int j = threadIdx.x;
  __shared__ __align__(16) float hg[HG];
  __shared__ float zsg[ZG];
  __shared__ float grp[BG * HG];
  __shared__ float za[ZA];
  __shared__ float haL[HA];
  __shared__ float res[BG * HA];

  float wg[HG];
  {
    const float* wr = cva + O_WHG + j * HG;
#pragma unroll
    for (int k = 0; k < HG; ++k) wg[k] = wr[k];
  }
  if (j < HG) hg[j] = 0.0f;
  float cg = 0.0f;
  __syncthreads();
  for (int b = 0; b < BG; ++b) {
    float acc = XZg[(size_t)b * ZG + j];
#pragma unroll
    for (int k = 0; k < HG; ++k) acc += wg[k] * hg[k];
    zsg[j] = acc;
    __syncthreads();
    if (j < HG) {
      float zi = zsg[j], zf = zsg[HG + j], zg = zsg[2 * HG + j], zo = zsg[3 * HG + j];
      cg = sigf(zf) * cg + sigf(zi) * tanh_(zg);
      float h = sigf(zo) * tanh_(cg);
      hg[j] = h;
      grp[b * HG + j] = fmaxf(h, 0.0f);
    }
    __syncthreads();
  }

  float wa2[HG];
  float wha[HA];
  if (j < ZA) {
#pragma unroll
    for (int k = 0; k < HG; ++k) wa2[k] = cva[O_WA + (HU + k) * 16 + j];
#pragma unroll
    for (int k = 0; k < HA; ++k) wha[k] = cva[O_WHA + j * HA + k];
  }
  if (j < HA) haL[j] = 0.0f;
  float ca = 0.0f;
  __syncthreads();
  for (int b = 0; b < BG; ++b) {
    if (j < ZA) {
      float acc = XZa[(size_t)b * ZA + j];
#pragma unroll
      for (int k = 0; k < HG; ++k) acc += wa2[k] * grp[b * HG + k];
#pragma unroll
      for (int k = 0; k < HA; ++k) acc += wha[k] * haL[k];
      za[j] = acc;
    }
    __syncthreads();
    if (j < HA) {
      float zi = za[j], zf = za[HA + j], zg = za[2 * HA + j], zo = za[3 * HA + j];
      ca = sigf(zf) * ca + sigf(zi) * tanh_(zg);
      float h = sigf(zo) * tanh_(ca);
      haL[j] = h;
      res[b * HA + j] = h;
    }
    __syncthreads();
  }
  if (j < BG) {
    float x0 = res[j * 4 + 0], x1 = res[j * 4 + 1];
    float x2 = res[j * 4 + 2], x3 = res[j * 4 + 3];
    float m = fmaxf(fmaxf(x0, x1), fmaxf(x2, x3));
    float e0 = __expf(x0 - m), e1 = __expf(x1 - m);
    float e2 = __expf(x2 - m), e3 = __expf(x3 - m);
    float s = e0 + e1 + e2 + e3;
    out[j * 4 + 0] = e0 / s;
    out[j * 4 + 1] = e1 / s;
    out[j * 4 + 2] = e2 / s;
    out[j * 4 + 3] = e3 / s;
  }
}

__global__ void k_zero(float* out) { out[threadIdx.x] = 0.0f; }

extern "C" void kernel_launch(void* const* d_in, const int* in_sizes, int n_in,
                              void* d_out, int out_size, void* d_ws, size_t ws_size,
                              hipStream_t stream) {
  const void* nodes = d_in[0];
  const int* eidx  = (const int*)d_in[2];
  const int* nn    = (const int*)d_in[3];
  const int* bidx  = (const int*)d_in[5];
  const int* who   = (const int*)d_in[6];

  if (ws_size < (size_t)WS_FLOATS * 4) {
    k_zero<<<1, 256, 0, stream>>>((float*)d_out);
    return;
  }

  float* ws = (float*)d_ws;
  int* flagp = (int*)d_ws;
  float* cva = ws + CV;
  float* XZmU = cva + O_XZM;   // 320 x 512 (unique per src node)
  float* msg  = cva + O_MSG;   // 1280 x 128
  float* XZu = cva + O_XZU;
  float* XZg = cva + O_XZG;
  float* XZa = cva + O_XZA;
  float* upd = cva + O_UPD;

  k_detect<<<1, 64, 0, stream>>>((const u32*)nodes, flagp);
  k_convert<<<(CONV_TOTAL + 255) / 256, 256, 0, stream>>>(
      nodes, d_in[1],
      d_in[7], d_in[8], d_in[9], d_in[10],
      d_in[11], d_in[12], d_in[13], d_in[14],
      d_in[15], d_in[16], d_in[17], d_in[18],
      d_in[19], d_in[20], d_in[21], d_in[22],
      flagp, cva);
  k_pre<<<2 * NNODE + BG, 256, 0, stream>>>(cva, nn, XZmU, XZu, XZg);
  k_chain2<NEDGE, true><<<1, 1024, 0, stream>>>(cva + O_WHM, XZmU, eidx, msg);
  k_aggfuse<<<NNODE, 256, 0, stream>>>(cva, msg, eidx, XZu);
  k_chain2<NNODE, false><<<1, 1024, 0, stream>>>(cva + O_WHU, XZu, nullptr, upd);
  k_gproj<<<2 * BG, 256, 0, stream>>>(cva, upd, bidx, who, XZg, XZa);
  k_final<<<1, 256, 0, stream>>>(cva, XZg, XZa, (float*)d_out);
}